// Round 8
// baseline (148.844 us; speedup 1.0000x reference)
//
#include <hip/hip_runtime.h>
#include <hip/hip_bf16.h>
#include <stdint.h>

#define HW_ 4096

typedef float f32x4 __attribute__((ext_vector_type(4)));
typedef short bf16x8 __attribute__((ext_vector_type(8)));

__device__ __forceinline__ unsigned short f2bf(float f) {
  __hip_bfloat16 h = __float2bfloat16(f);
  return *reinterpret_cast<unsigned short*>(&h);
}
__device__ __forceinline__ float sigmoidf_(float x) { return 1.f / (1.f + __expf(-x)); }

__device__ __forceinline__ void glds16(const void* g, void* l) {
  __builtin_amdgcn_global_load_lds(
      (const __attribute__((address_space(1))) unsigned int*)g,
      (__attribute__((address_space(3))) unsigned int*)l, 16, 0, 0);
}

// ---- 1. single pass over x (float4 loads): per-(b,c) partial mean/max + bf16
//         transpose to xtr[b][hw][c] (16B stores) ----
__global__ void k_pre(const float* __restrict__ x, unsigned short* __restrict__ xtr,
                      float* __restrict__ psum, float* __restrict__ pmax) {
  int hwb = blockIdx.x;  // 64 hw per block
  int cb = blockIdx.y;   // 64 c per block
  int b = blockIdx.z;
  int t = threadIdx.x;
  __shared__ float sv[64][65];
  int h16 = t & 15, g = t >> 4;
#pragma unroll
  for (int i = 0; i < 4; ++i) {
    int c_l = g + i * 16;
    float4 v = *reinterpret_cast<const float4*>(
        x + (((size_t)b * 256 + cb * 64 + c_l) << 12) + hwb * 64 + h16 * 4);
    *reinterpret_cast<float4*>(&sv[c_l][h16 * 4]) = v;
  }
  __syncthreads();
  {
    int c_l = t >> 2, q = t & 3;
    float s16 = 0.f, m16 = -3.4e38f;
#pragma unroll
    for (int j = 0; j < 16; ++j) {
      float vv = sv[c_l][q * 16 + j];
      s16 += vv; m16 = fmaxf(m16, vv);
    }
    s16 += __shfl_xor(s16, 1); s16 += __shfl_xor(s16, 2);
    m16 = fmaxf(m16, __shfl_xor(m16, 1)); m16 = fmaxf(m16, __shfl_xor(m16, 2));
    if (q == 0) {
      int c = cb * 64 + c_l;
      psum[(((size_t)b * 256 + c) << 6) + hwb] = s16;
      pmax[(((size_t)b * 256 + c) << 6) + hwb] = m16;
    }
  }
  // transpose to xtr (bf16, pixel-major), 16B per store
#pragma unroll
  for (int i = 0; i < 2; ++i) {
    int fp = t + i * 256;
    int hw2 = fp >> 3;        // 0..63
    int cp = (fp & 7) * 8;    // 0..56
    uint4 uu;
    uu.x = (unsigned)f2bf(sv[cp + 0][hw2]) | ((unsigned)f2bf(sv[cp + 1][hw2]) << 16);
    uu.y = (unsigned)f2bf(sv[cp + 2][hw2]) | ((unsigned)f2bf(sv[cp + 3][hw2]) << 16);
    uu.z = (unsigned)f2bf(sv[cp + 4][hw2]) | ((unsigned)f2bf(sv[cp + 5][hw2]) << 16);
    uu.w = (unsigned)f2bf(sv[cp + 6][hw2]) | ((unsigned)f2bf(sv[cp + 7][hw2]) << 16);
    *reinterpret_cast<uint4*>(xtr + (((size_t)b * 4096 + hwb * 64 + hw2) << 8) + cb * 64 + cp) = uu;
  }
}

// ---- 2. small per-batch math (vectorized; + zero BN accumulators + zero page) ----
__global__ void k_tiny(const float* __restrict__ psum, const float* __restrict__ pmax,
                       const float* __restrict__ aw3, const float* __restrict__ Wout,
                       const float* __restrict__ Wk, const float* __restrict__ lw3,
                       const float* __restrict__ lbia, const float* __restrict__ mw1,
                       const float* __restrict__ mw2,
                       float* __restrict__ in_att, float* __restrict__ out_att,
                       float* __restrict__ katt, float* __restrict__ sc,
                       float* __restrict__ sums, float* __restrict__ zerop) {
  int b = blockIdx.x, t = threadIdx.x;
  __shared__ float g[256], tt[256], red[256], hsum[16], ksm[4], mx[128];
  {
    const float4* pp = reinterpret_cast<const float4*>(psum + ((size_t)(b * 256 + t) << 6));
    const float4* pm = reinterpret_cast<const float4*>(pmax + ((size_t)(b * 256 + t) << 6));
    float s = 0.f, m = -3.4e38f;
#pragma unroll
    for (int j = 0; j < 16; ++j) {
      float4 a = pp[j]; s += (a.x + a.y) + (a.z + a.w);
      float4 q4 = pm[j];
      m = fmaxf(m, fmaxf(fmaxf(q4.x, q4.y), fmaxf(q4.z, q4.w)));
    }
    g[t] = s * (1.f / 4096.f);
    if (t >= 128) mx[t - 128] = m;
  }
  if (b == 0) {
    sums[t] = 0.f; sums[256 + t] = 0.f;
    zerop[t] = 0.f;
  }
  __syncthreads();
  float c0 = aw3[0], c1 = aw3[1], c2 = aw3[2];
  float tv = c1 * g[t];
  if (t > 0) tv += c0 * g[t - 1];
  if (t < 255) tv += c2 * g[t + 1];
  tt[t] = tv;
  in_att[b * 256 + t] = sigmoidf_(tv);
  __syncthreads();
  {
    float d = 0.f;
    const float4* wr = reinterpret_cast<const float4*>(Wout + (size_t)t * 256);
    for (int c4 = 0; c4 < 64; ++c4) {
      float4 wv4 = wr[c4];
      d += tt[c4 * 4] * wv4.x + tt[c4 * 4 + 1] * wv4.y + tt[c4 * 4 + 2] * wv4.z + tt[c4 * 4 + 3] * wv4.w;
    }
    out_att[b * 256 + t] = sigmoidf_(d);
  }
  int k = t >> 6, lane = t & 63;
  {
    float pk = 0.f;
    for (int c = lane; c < 256; c += 64) pk += tt[c] * Wk[k * 256 + c];
    red[t] = pk; __syncthreads();
    for (int off = 32; off > 0; off >>= 1) {
      if (lane < off) red[t] += red[t + off];
      __syncthreads();
    }
    if (t == 0) {
      float l0 = red[0], l1 = red[64], l2 = red[128], l3 = red[192];
      float mm = fmaxf(fmaxf(l0, l1), fmaxf(l2, l3));
      float e0 = __expf(l0 - mm), e1 = __expf(l1 - mm), e2 = __expf(l2 - mm), e3 = __expf(l3 - mm);
      float inv = 1.f / (e0 + e1 + e2 + e3);
      ksm[0] = e0 * inv; ksm[1] = e1 * inv; ksm[2] = e2 * inv; ksm[3] = e3 * inv;
    }
    __syncthreads();
    if (t < 4) katt[b * 4 + t] = ksm[t];
  }
  if (t < 128) {
    float a0 = lw3[0], a1 = lw3[1], a2 = lw3[2];
    float sv = a1 * g[t] + lbia[0];
    if (t > 0) sv += a0 * g[t - 1];
    if (t < 127) sv += a2 * g[t + 1];
    sc[b * 256 + t] = sigmoidf_(sv);
  }
  __syncthreads();
  if (t < 16) {
    float d1 = 0.f, d2 = 0.f;
    const float* w1r = mw1 + t * 128;
    for (int j = 0; j < 128; ++j) { d1 += mx[j] * w1r[j]; d2 += g[128 + j] * w1r[j]; }
    hsum[t] = fmaxf(d1, 0.f) + fmaxf(d2, 0.f);
  }
  __syncthreads();
  if (t < 128) {
    float dd = 0.f;
    const float* w2r = mw2 + t * 16;
    for (int r = 0; r < 16; ++r) dd += hsum[r] * w2r[r];
    sc[b * 256 + 128 + t] = sigmoidf_(dd);
  }
}

// ---- 3. aggregate bank weights: LDS-tile ede per output channel o, apply all 16 b ----
// agg[(b*256+o)*2304 + pq*256 + i] = (sum_k katt[b,k]*ede[k,o,i,pq]) * in_att[b,i]
__global__ __launch_bounds__(256) void k_agg(const float* __restrict__ ede,
                                             const float* __restrict__ katt,
                                             const float* __restrict__ inatt,
                                             unsigned short* __restrict__ agg) {
  __shared__ float eds[4][2304];
  int o = blockIdx.x, t = threadIdx.x;
#pragma unroll
  for (int k = 0; k < 4; ++k) {
    const float* src = ede + ((size_t)k * 256 + o) * 2304;
#pragma unroll
    for (int j = 0; j < 9; ++j) eds[k][j * 256 + t] = src[j * 256 + t];
  }
  __syncthreads();
  int ii = (t & 127) * 2;
  int bh = t >> 7;
  for (int b2 = 0; b2 < 8; ++b2) {
    int b = b2 * 2 + bh;
    float k0 = katt[b * 4], k1 = katt[b * 4 + 1], k2 = katt[b * 4 + 2], k3 = katt[b * 4 + 3];
    float ia0 = inatt[b * 256 + ii], ia1 = inatt[b * 256 + ii + 1];
    size_t obase = ((size_t)(b * 256 + o) * 9) << 8;
#pragma unroll
    for (int pq = 0; pq < 9; ++pq) {
      float v0 = k0 * eds[0][ii * 9 + pq] + k1 * eds[1][ii * 9 + pq] +
                 k2 * eds[2][ii * 9 + pq] + k3 * eds[3][ii * 9 + pq];
      float v1 = k0 * eds[0][(ii + 1) * 9 + pq] + k1 * eds[1][(ii + 1) * 9 + pq] +
                 k2 * eds[2][(ii + 1) * 9 + pq] + k3 * eds[3][(ii + 1) * 9 + pq];
      v0 *= ia0; v1 *= ia1;
      unsigned int u = (unsigned)f2bf(v0) | ((unsigned)f2bf(v1) << 16);
      *reinterpret_cast<unsigned int*>(agg + obase + (pq << 8) + ii) = u;
    }
  }
}

// ---- 4. slab-reuse implicit-GEMM conv, 3-taps-per-barrier phases ----
// BM=256 (o), BN=256 px (4 image rows), 8 waves (2Mx4N). 24 phases = 8 ch-steps x
// 3 slab rows (dp). Per phase: stage next phase's 3 A-tiles (+next slab at c edge),
// compute 3x{8 A-reads + 4 B-reads + 32 MFMA}, then vmcnt(0)+barrier (loads issued
// at phase top land during ~2500cyc compute, so the drain is ~free). LDS: A = 2
// regions x 3 tiles x 16KB = 96KB; slab = 2 x 24KB = 48KB; total 144KB, 1 block/CU.
__global__ __launch_bounds__(512, 2) void k_conv(
    const unsigned short* __restrict__ agg, const unsigned short* __restrict__ xtr,
    const float* __restrict__ x, const float* __restrict__ oatt,
    const float* __restrict__ sc, const float* __restrict__ zerop,
    float* __restrict__ sums, float* __restrict__ zout) {
  __shared__ __align__(16) char smem[147456];
  int wg = blockIdx.x;
  int bswz = ((wg & 7) << 5) | (wg >> 3);  // 2 batches per XCD
  int b = bswz >> 4, pt = bswz & 15;
  int tid = threadIdx.x;
  int l = tid & 63;
  int wv = tid >> 6;
  int wm = wv >> 2, wn = wv & 3;          // wn = wave's image row (0..3)
  int w0 = l & 15, ks = l >> 4;
  bool maskl0 = (w0 == 0), maskl15 = (w0 == 15);

  // A staging geometry (2 x 16B per thread per A-tile), pre-swizzled source
  int r0 = tid >> 2, s0 = tid & 3;
  int r1 = r0 + 128;
  int f0 = (s0 ^ ((r0 >> 1) & 3)) << 3;
  int f1 = (s0 ^ ((r1 >> 1) & 3)) << 3;
  const unsigned short* aS0 = agg + (size_t)(b * 256 + r0) * 2304 + f0;
  const unsigned short* aS1 = agg + (size_t)(b * 256 + r1) * 2304 + f1;

  // slab staging sources (3 x 16B per thread per c-step), pre-swizzled, border->zero
  auto slabsrc = [&](int j) -> const char* {
    int idx = j * 512 + tid;
    int P = idx >> 2, sp = idx & 3;
    int sr = P >> 6, w = P & 63;
    int imgrow = pt * 4 + sr - 1;
    int ir = imgrow < 0 ? 0 : (imgrow > 63 ? 63 : imgrow);
    int slog = sp ^ ((w >> 1) & 3);
    const char* gp = (const char*)(xtr + (((size_t)b * 4096 + ir * 64 + w) << 8) + slog * 8);
    return ((unsigned)imgrow < 64u) ? gp : (const char*)zerop;
  };
  const char* sb0_ = slabsrc(0);
  const char* sb1_ = slabsrc(1);
  const char* sb2_ = slabsrc(2);

  // A fragment read offsets (swizzled), within a 16KB A tile
  int aOff[8];
#pragma unroll
  for (int fm = 0; fm < 8; ++fm) {
    int R = wm * 128 + fm * 16 + (l & 15);
    aOff[fm] = R * 64 + (((l >> 4) ^ ((R >> 1) & 3)) << 4);
  }

  f32x4 acc[8][4];
  f32x4 zero4 = {0.f, 0.f, 0.f, 0.f};
#pragma unroll
  for (int i2 = 0; i2 < 8; ++i2)
#pragma unroll
    for (int j2 = 0; j2 < 4; ++j2) acc[i2][j2] = zero4;

  bf16x8 z8 = {0, 0, 0, 0, 0, 0, 0, 0};

  // ---- prologue: slab(c=0) + A3(phase 0) into region 0; drain; publish ----
  {
    char* sd = smem + 98304;
    glds16(sb0_, sd + tid * 16);
    glds16(sb1_, sd + 8192 + tid * 16);
    glds16(sb2_, sd + 16384 + tid * 16);
    char* ar = smem;
#pragma unroll
    for (int dq = 0; dq < 3; ++dq) {
      glds16(aS0 + dq * 256, ar + dq * 16384 + tid * 16);
      glds16(aS1 + dq * 256, ar + dq * 16384 + 8192 + tid * 16);
    }
  }
  asm volatile("s_waitcnt vmcnt(0)" ::: "memory");
  __builtin_amdgcn_s_barrier();

  // ---- 24 phases ----
  int ph = 0;
  for (int c = 0; c < 8; ++c) {
    const char* sb = smem + 98304 + ((c & 1) ? 24576 : 0);
    for (int dp = 0; dp < 3; ++dp, ++ph) {
      // stage next phase's 3 A-tiles into the other region
      if (ph < 23) {
        int nc = (dp == 2) ? c + 1 : c;
        int ndp = (dp == 2) ? 0 : dp + 1;
        char* ar = smem + ((ph + 1) & 1) * 49152;
#pragma unroll
        for (int dq = 0; dq < 3; ++dq) {
          int cols = (ndp * 3 + dq) * 256 + nc * 32;
          glds16(aS0 + cols, ar + dq * 16384 + tid * 16);
          glds16(aS1 + cols, ar + dq * 16384 + 8192 + tid * 16);
        }
      }
      // stage next c's slab during the last dp of current c
      if (dp == 2 && c < 7) {
        char* sd = smem + 98304 + (((c + 1) & 1) ? 24576 : 0);
        glds16(sb0_ + (c + 1) * 64, sd + tid * 16);
        glds16(sb1_ + (c + 1) * 64, sd + 8192 + tid * 16);
        glds16(sb2_ + (c + 1) * 64, sd + 16384 + tid * 16);
      }
      // compute: 3 taps (dq) x 32 MFMA from region ph&1 + slab row wn+dp
      const char* abase = smem + (ph & 1) * 49152;
      int rowb = (wn + dp) << 6;
#pragma unroll
      for (int dq = 0; dq < 3; ++dq) {
        const char* ab = abase + dq * 16384;
        bf16x8 af[8], bv[4];
#pragma unroll
        for (int f = 0; f < 8; ++f) af[f] = *reinterpret_cast<const bf16x8*>(ab + aOff[f]);
#pragma unroll
        for (int fn = 0; fn < 4; ++fn) {
          int wcol = w0 + fn * 16 + (dq - 1);
          int wc = wcol < 0 ? 0 : (wcol > 63 ? 63 : wcol);
          int bo = ((rowb + wc) << 6) + ((ks ^ ((wc >> 1) & 3)) << 4);
          bv[fn] = *reinterpret_cast<const bf16x8*>(sb + bo);
        }
        if (dq == 0) bv[0] = maskl0 ? z8 : bv[0];
        if (dq == 2) bv[3] = maskl15 ? z8 : bv[3];
        __builtin_amdgcn_s_setprio(1);
#pragma unroll
        for (int fm = 0; fm < 8; ++fm)
#pragma unroll
          for (int fn = 0; fn < 4; ++fn)
            acc[fm][fn] = __builtin_amdgcn_mfma_f32_16x16x32_bf16(af[fm], bv[fn], acc[fm][fn], 0, 0, 0);
        __builtin_amdgcn_s_setprio(0);
      }
      // drain this phase's staging (landed during compute), publish to all waves
      asm volatile("s_waitcnt vmcnt(0)" ::: "memory");
      __builtin_amdgcn_s_barrier();
    }
  }
  __syncthreads();

  // ---- epilogue: z = Q*out_att + x[oc]*sc[oc]; fused BN partial sums ----
  float* ls = (float*)smem;  // [256] sum, [256] sumsq
  ls[tid] = 0.f;
  __syncthreads();

#pragma unroll
  for (int fm = 0; fm < 8; ++fm) {
#pragma unroll
    for (int r = 0; r < 4; ++r) {
      int m = wm * 128 + fm * 16 + ((l >> 4) << 2) + r;
      int oc = ((m & 3) << 6) | (m >> 2);
      float oav = oatt[b * 256 + m];
      float scv = sc[b * 256 + oc];
      const float* xrow = x + (((size_t)b * 256 + oc) << 12) + pt * 256;
      float* zrow = zout + (((size_t)b * 256 + m) << 12) + pt * 256;
      float psv = 0.f, psv2 = 0.f;
#pragma unroll
      for (int fn = 0; fn < 4; ++fn) {
        int n = wn * 64 + fn * 16 + (l & 15);
        float zv = acc[fm][fn][r] * oav + xrow[n] * scv;
        zrow[n] = zv;
        psv += zv; psv2 += zv * zv;
      }
#pragma unroll
      for (int d = 8; d > 0; d >>= 1) {
        psv += __shfl_down(psv, d, 16);
        psv2 += __shfl_down(psv2, d, 16);
      }
      if ((l & 15) == 0) {
        atomicAdd(&ls[m], psv);
        atomicAdd(&ls[256 + m], psv2);
      }
    }
  }
  __syncthreads();
  if (tid < 256) {
    atomicAdd(&sums[tid], ls[tid]);
    atomicAdd(&sums[256 + tid], ls[256 + tid]);
  }
}

// ---- 5. BN finalize + apply + ReLU (in place on d_out) ----
__global__ void k_apply(float* __restrict__ z, const float* __restrict__ sums,
                        const float* __restrict__ gamma, const float* __restrict__ beta) {
  int idx = blockIdx.x * 256 + threadIdx.x;
  for (int i = idx; i < 4194304; i += 4096 * 256) {
    int c = (i >> 10) & 255;
    float mean = sums[c] * (1.f / 65536.f);
    float var = sums[256 + c] * (1.f / 65536.f) - mean * mean;
    float scale = gamma[c] * rsqrtf(var + 1e-5f);
    float shift = beta[c] - mean * scale;
    float4* p = reinterpret_cast<float4*>(z) + i;
    float4 v = *p;
    v.x = fmaxf(v.x * scale + shift, 0.f);
    v.y = fmaxf(v.y * scale + shift, 0.f);
    v.z = fmaxf(v.z * scale + shift, 0.f);
    v.w = fmaxf(v.w * scale + shift, 0.f);
    *p = v;
  }
}

extern "C" void kernel_launch(void* const* d_in, const int* in_sizes, int n_in,
                              void* d_out, int out_size, void* d_ws, size_t ws_size,
                              hipStream_t stream) {
  (void)in_sizes; (void)n_in; (void)out_size; (void)ws_size;
  const float* x = (const float*)d_in[0];
  const float* aw3 = (const float*)d_in[1];
  const float* Wout = (const float*)d_in[2];
  const float* Wk = (const float*)d_in[3];
  const float* ede = (const float*)d_in[4];
  const float* lw3 = (const float*)d_in[5];
  const float* lbia = (const float*)d_in[6];
  const float* mw1 = (const float*)d_in[7];
  const float* mw2 = (const float*)d_in[8];
  const float* gamma = (const float*)d_in[9];
  const float* beta = (const float*)d_in[10];

  char* ws = (char*)d_ws;
  float* inatt = (float*)(ws + 32768);
  float* oatt  = (float*)(ws + 49152);
  float* katt  = (float*)(ws + 65536);
  float* sc    = (float*)(ws + 65792);   // 16KB -> ends 82176
  float* zerop = (float*)(ws + 82176);   // 1KB zero page
  float* sums  = (float*)(ws + 83200);   // 2KB BN accumulators
  unsigned short* xtr = (unsigned short*)(ws + 262144);                // 32MB
  unsigned short* agg = (unsigned short*)(ws + 262144 + 33554432);     // 18.9MB
  // psum/pmax alias the agg region (consumed by k_tiny before k_agg writes agg)
  float* psum = (float*)(ws + 262144 + 33554432);                      // 1MB
  float* pmax = (float*)(ws + 262144 + 33554432 + 1048576);            // 1MB
  float* z = (float*)d_out;

  k_pre<<<dim3(64, 4, 16), 256, 0, stream>>>(x, xtr, psum, pmax);
  k_tiny<<<16, 256, 0, stream>>>(psum, pmax, aw3, Wout, Wk, lw3, lbia, mw1, mw2,
                                 inatt, oatt, katt, sc, sums, zerop);
  k_agg<<<256, 256, 0, stream>>>(ede, katt, inatt, agg);
  k_conv<<<256, 512, 0, stream>>>(agg, xtr, x, oatt, sc, zerop, sums, z);
  k_apply<<<4096, 256, 0, stream>>>(z, sums, gamma, beta);
}